// Round 4
// baseline (318.468 us; speedup 1.0000x reference)
//
#include <hip/hip_runtime.h>

// HashEmbeddingBag: out[b, j] = sum_{t in bag b} hashed_weight[(x[t]*64 + j) % HSIZE]
// HSIZE % 64 == 0 -> each virtual row is a contiguous 256B slice of hashed_weight.
// weight_idx input (d_in[1]) is the pure function (i*64+j) % HSIZE -> computed
// arithmetically, never read (saves a 52 MB gather from a 256 MB HBM table).
//
// Layout: one wave per bag. Lanes split into 4 groups of 16; each group loads a
// whole row as float4 (16 lanes x 16B = 256B), so one global_load_dwordx4
// instruction fetches 4 rows = 1 KB. The n==50 bench path is fully unrolled so
// ~12 gather loads are in flight per wave (latency hiding); groups are reduced
// with __shfl_xor(16/32) and lanes 0-15 store one float4 each.

#define DIM 64
#define HSIZE 16000000

__global__ __launch_bounds__(256) void hash_embedding_bag_kernel(
    const float* __restrict__ hashed_weight,
    const int* __restrict__ x,
    const int* __restrict__ offsets,
    float* __restrict__ out,
    int num_bags, int total)
{
    const int wave = threadIdx.x >> 6;           // 4 waves per block
    const int lane = threadIdx.x & 63;
    const int bag  = blockIdx.x * 4 + wave;
    if (bag >= num_bags) return;

    const int g = lane >> 4;                     // row-group 0..3
    const int s = lane & 15;                     // sub-lane: covers dims s*4 .. s*4+3

    const int start = offsets[bag];
    const int end   = (bag + 1 < num_bags) ? offsets[bag + 1] : total;
    const int n     = end - start;

    float4 acc = make_float4(0.f, 0.f, 0.f, 0.f);
    const float* __restrict__ hw = hashed_weight;

    if (n == 50) {
        // 12 fully-unrolled rounds of 4 rows each (rows 0..47)
        #pragma unroll
        for (int r = 0; r < 48; r += 4) {
            int   xi   = x[start + r + g];
            int   base = (xi * DIM) % HSIZE;     // multiple of 64, no wrap within row
            float4 v   = *reinterpret_cast<const float4*>(hw + base + s * 4);
            acc.x += v.x; acc.y += v.y; acc.z += v.z; acc.w += v.w;
        }
        // tail rows 48, 49 handled by groups 0 and 1
        if (g < 2) {
            int   xi   = x[start + 48 + g];
            int   base = (xi * DIM) % HSIZE;
            float4 v   = *reinterpret_cast<const float4*>(hw + base + s * 4);
            acc.x += v.x; acc.y += v.y; acc.z += v.z; acc.w += v.w;
        }
    } else {
        for (int r = 0; r < n; r += 4) {
            int row = r + g;
            if (row < n) {
                int   xi   = x[start + row];
                int   base = (xi * DIM) % HSIZE;
                float4 v   = *reinterpret_cast<const float4*>(hw + base + s * 4);
                acc.x += v.x; acc.y += v.y; acc.z += v.z; acc.w += v.w;
            }
        }
    }

    // reduce over the 4 row-groups: lanes differing in bits 4 and 5
    acc.x += __shfl_xor(acc.x, 16);
    acc.y += __shfl_xor(acc.y, 16);
    acc.z += __shfl_xor(acc.z, 16);
    acc.w += __shfl_xor(acc.w, 16);
    acc.x += __shfl_xor(acc.x, 32);
    acc.y += __shfl_xor(acc.y, 32);
    acc.z += __shfl_xor(acc.z, 32);
    acc.w += __shfl_xor(acc.w, 32);

    if (lane < 16) {
        *reinterpret_cast<float4*>(out + bag * DIM + s * 4) = acc;
    }
}

extern "C" void kernel_launch(void* const* d_in, const int* in_sizes, int n_in,
                              void* d_out, int out_size, void* d_ws, size_t ws_size,
                              hipStream_t stream) {
    const float* hashed_weight = (const float*)d_in[0];
    // d_in[1] = weight_idx (pure function; computed arithmetically, not read)
    const int* x       = (const int*)d_in[2];
    const int* offsets = (const int*)d_in[3];
    float* out = (float*)d_out;

    const int total    = in_sizes[2];
    const int num_bags = in_sizes[3];

    const int waves_per_block = 4;
    const int blocks = (num_bags + waves_per_block - 1) / waves_per_block;
    hash_embedding_bag_kernel<<<blocks, waves_per_block * 64, 0, stream>>>(
        hashed_weight, x, offsets, out, num_bags, total);
}

// Round 7
// 317.673 us; speedup vs baseline: 1.0025x; 1.0025x over previous
//
#include <hip/hip_runtime.h>

// HashEmbeddingBag: out[b, j] = sum_{t in bag b} hashed_weight[(x[t]*64 + j) % HSIZE]
// HSIZE % 64 == 0 -> each virtual row is a contiguous 256B slice of hashed_weight.
// weight_idx (d_in[1]) is the pure function (i*64+j) % HSIZE -> computed
// arithmetically, never read.
//
// 2 waves per bag (even/odd rows), 2 bags per 256-thread block ->
// 2048 blocks = 8 blocks/CU = 32 waves/CU (max occupancy), halving each wave's
// exposed gather-latency chain. Within a wave: 4 groups of 16 lanes, each group
// loads one row per round as float4 (16 x 16B = 256B row). Reduce: shfl_xor
// (16,32) within wave, then LDS add across the bag's two waves.

#define DIM 64
#define HSIZE 16000000

__global__ __launch_bounds__(256) void hash_embedding_bag_kernel(
    const float* __restrict__ hashed_weight,
    const int* __restrict__ x,
    const int* __restrict__ offsets,
    float* __restrict__ out,
    int num_bags, int total)
{
    __shared__ float4 part[2][16];               // per-bag-slot cross-wave partials

    const int wave    = threadIdx.x >> 6;        // 0..3
    const int lane    = threadIdx.x & 63;
    const int bagslot = wave >> 1;               // 0,1
    const int half    = wave & 1;                // even/odd row stream
    const int bag     = blockIdx.x * 2 + bagslot;
    const bool active = (bag < num_bags);

    const int g = lane >> 4;                     // row-group 0..3
    const int s = lane & 15;                     // sub-lane: dims s*4 .. s*4+3

    float4 acc = make_float4(0.f, 0.f, 0.f, 0.f);
    const float* __restrict__ hw = hashed_weight;

    if (active) {
        const int start = offsets[bag];
        const int end   = (bag + 1 < num_bags) ? offsets[bag + 1] : total;
        const int n     = end - start;

        if (n == 50) {
            // rows r = 8*j + 2*g + half ; j=0..5 covers rows 0..47 across all
            // groups; tail rows 48(+half) handled by group 0.
            #pragma unroll
            for (int j = 0; j < 6; ++j) {
                int   r    = 8 * j + 2 * g + half;
                int   xi   = x[start + r];
                int   base = (xi * DIM) % HSIZE; // multiple of 64, no wrap in-row
                float4 v   = *reinterpret_cast<const float4*>(hw + base + s * 4);
                acc.x += v.x; acc.y += v.y; acc.z += v.z; acc.w += v.w;
            }
            if (g == 0) {
                int   xi   = x[start + 48 + half];
                int   base = (xi * DIM) % HSIZE;
                float4 v   = *reinterpret_cast<const float4*>(hw + base + s * 4);
                acc.x += v.x; acc.y += v.y; acc.z += v.z; acc.w += v.w;
            }
        } else {
            for (int r = 2 * g + half; r < n; r += 8) {
                int   xi   = x[start + r];
                int   base = (xi * DIM) % HSIZE;
                float4 v   = *reinterpret_cast<const float4*>(hw + base + s * 4);
                acc.x += v.x; acc.y += v.y; acc.z += v.z; acc.w += v.w;
            }
        }
    }

    // reduce across the 4 row-groups within this wave
    acc.x += __shfl_xor(acc.x, 16);
    acc.y += __shfl_xor(acc.y, 16);
    acc.z += __shfl_xor(acc.z, 16);
    acc.w += __shfl_xor(acc.w, 16);
    acc.x += __shfl_xor(acc.x, 32);
    acc.y += __shfl_xor(acc.y, 32);
    acc.z += __shfl_xor(acc.z, 32);
    acc.w += __shfl_xor(acc.w, 32);

    // cross-wave (even/odd halves) reduce via LDS
    if (half == 0 && lane < 16) part[bagslot][s] = acc;
    __syncthreads();
    if (active && half == 1 && lane < 16) {
        float4 p = part[bagslot][s];
        acc.x += p.x; acc.y += p.y; acc.z += p.z; acc.w += p.w;
        *reinterpret_cast<float4*>(out + bag * DIM + s * 4) = acc;
    }
}

extern "C" void kernel_launch(void* const* d_in, const int* in_sizes, int n_in,
                              void* d_out, int out_size, void* d_ws, size_t ws_size,
                              hipStream_t stream) {
    const float* hashed_weight = (const float*)d_in[0];
    // d_in[1] = weight_idx (pure function; computed arithmetically, not read)
    const int* x       = (const int*)d_in[2];
    const int* offsets = (const int*)d_in[3];
    float* out = (float*)d_out;

    const int total    = in_sizes[2];
    const int num_bags = in_sizes[3];

    const int bags_per_block = 2;
    const int blocks = (num_bags + bags_per_block - 1) / bags_per_block;
    hash_embedding_bag_kernel<<<blocks, 256, 0, stream>>>(
        hashed_weight, x, offsets, out, num_bags, total);
}